// Round 1
// baseline (154.883 us; speedup 1.0000x reference)
//
#include <hip/hip_runtime.h>
#include <hip/hip_bf16.h>
#include <cstdint>

#define B_ 2048
#define N_ 4096
#define D_ 256
#define P_ 100
#define K_ 30
#define INVT 5.0f

typedef __attribute__((ext_vector_type(8))) short bf16x8;
typedef __attribute__((ext_vector_type(4))) float f32x4;

__device__ __forceinline__ float waveReduceSum(float v) {
#pragma unroll
  for (int off = 32; off > 0; off >>= 1) v += __shfl_xor(v, off, 64);
  return v;
}

__device__ __forceinline__ float blockReduceSum256(float v, float* s4) {
  int lane = threadIdx.x & 63, w = threadIdx.x >> 6;
  v = waveReduceSum(v);
  __syncthreads();              // protect s4 reuse
  if (lane == 0) s4[w] = v;
  __syncthreads();
  return s4[0] + s4[1] + s4[2] + s4[3];
}

// ---------------- init: zero accumulators ----------------
__global__ void init_kernel(float* sums) {
  if (threadIdx.x < 2) sums[threadIdx.x] = 0.f;
}

// ---------------- normalize x / x_aug rows, pos dots ----------------
__global__ void norm_kernel(const float* __restrict__ x, const float* __restrict__ xa,
                            __hip_bfloat16* __restrict__ outb, float* __restrict__ sums) {
  __shared__ float s4[4];
  int i = blockIdx.x, t = threadIdx.x;
  float a = x[i * D_ + t];
  float ss = blockReduceSum256(a * a, s4);
  float o1 = a / fmaxf(sqrtf(ss), 1e-12f);
  outb[i * D_ + t] = __float2bfloat16(o1);
  float b = xa[i * D_ + t];
  float ss2 = blockReduceSum256(b * b, s4);
  float o2 = b / fmaxf(sqrtf(ss2), 1e-12f);
  outb[(B_ + i) * D_ + t] = __float2bfloat16(o2);
  float d = blockReduceSum256(o1 * o2, s4);
  if (t == 0) atomicAdd(&sums[1], d);
}

// ---------------- normalize prototypes ----------------
__global__ void pnorm_kernel(const float* __restrict__ pw, float* __restrict__ w) {
  __shared__ float s4[4];
  int p = blockIdx.x, t = threadIdx.x;
  float a = pw[p * D_ + t];
  float ss = blockReduceSum256(a * a, s4);
  w[p * D_ + t] = a / fmaxf(sqrtf(ss), 1e-12f);
}

// ---------------- proto_dist = w @ w.T (100x100) ----------------
__global__ void pd_kernel(const float* __restrict__ w, float* __restrict__ pd) {
  __shared__ float wq[D_];
  int q = blockIdx.x, t = threadIdx.x, lane = t & 63, wv = t >> 6;
  wq[t] = w[q * D_ + t];
  __syncthreads();
  for (int r = wv; r < P_; r += 4) {
    const float* wr = w + r * D_;
    float s = 0.f;
#pragma unroll
    for (int e = 0; e < 4; ++e) s += wq[lane * 4 + e] * wr[lane * 4 + e];
    s = waveReduceSum(s);
    if (lane == 0) pd[q * P_ + r] = s;
  }
}

// ---------------- histogram of hard_q + concat hq ----------------
__global__ void hist_kernel(const int* __restrict__ hq1, const int* __restrict__ hq2,
                            int* __restrict__ hq, int* __restrict__ cnt) {
  __shared__ int c[P_];
  int t = threadIdx.x;
  if (t < P_) c[t] = 0;
  __syncthreads();
  for (int i = t; i < N_; i += 256) {
    int q = (i < B_) ? hq1[i] : hq2[i - B_];
    hq[i] = q;
    atomicAdd(&c[q], 1);
  }
  __syncthreads();
  if (t < P_) cnt[t] = c[t];
}

// ---------------- per-row Gtab[i][p] = member ? reweight : 0 ----------------
__global__ void gtab_kernel(const int* __restrict__ hq, const int* __restrict__ cnt,
                            const float* __restrict__ pd, const int* __restrict__ nq1,
                            const int* __restrict__ nq2, float* __restrict__ gtab) {
  __shared__ unsigned char memb[4][104];
  int wv = threadIdx.x >> 6, lane = threadIdx.x & 63;
  int i = blockIdx.x * 4 + wv;
  int q = hq[i];
  if (lane < 52) { memb[wv][lane * 2] = 0; memb[wv][lane * 2 + 1] = 0; }
  __syncthreads();
  const int* nrow = (i < B_) ? (nq1 + i * K_) : (nq2 + (i - B_) * K_);
  if (lane < K_) memb[wv][nrow[lane]] = 1;
  __syncthreads();

  int p0 = lane, p1 = lane + 64;
  bool has1 = (p1 < P_);
  float v0 = pd[q * P_ + p0];
  int m0 = cnt[p0] - (p0 == q ? 1 : 0);
  float v1 = 0.f; int m1 = 0;
  if (has1) { v1 = pd[q * P_ + p1]; m1 = cnt[p1] - (p1 == q ? 1 : 0); }

  float mn = 1e30f, mx = -1e30f;
  if (m0 > 0) { mn = fminf(mn, v0); mx = fmaxf(mx, v0); }
  if (has1 && m1 > 0) { mn = fminf(mn, v1); mx = fmaxf(mx, v1); }
#pragma unroll
  for (int off = 32; off > 0; off >>= 1) {
    mn = fminf(mn, __shfl_xor(mn, off, 64));
    mx = fmaxf(mx, __shfl_xor(mx, off, 64));
  }
  float rmin = fminf(0.f, mn);
  float rmax = fmaxf(rmin, mx);
  float inv = 1.f / (rmax - rmin);
  float r0 = (v0 - rmin) * inv, r1 = (v1 - rmin) * inv;
  float s1 = (m0 > 0 ? (float)m0 * r0 : 0.f) + ((has1 && m1 > 0) ? (float)m1 * r1 : 0.f);
  s1 = waveReduceSum(s1);
  float mu = s1 / (float)N_;
  float ss = (m0 > 0 ? (float)m0 * (r0 - mu) * (r0 - mu) : 0.f) +
             ((has1 && m1 > 0) ? (float)m1 * (r1 - mu) * (r1 - mu) : 0.f);
  ss = waveReduceSum(ss);
  ss += mu * mu;  // diagonal slot (value 0)
  float var = ss / (float)(N_ - 1);
  float i2v = 1.f / (2.f * var);
  float g0 = memb[wv][p0] ? __expf((r0 - mu) * (r0 - mu) * i2v) : 0.f;
  gtab[i * P_ + p0] = g0;
  if (has1) {
    float g1 = memb[wv][p1] ? __expf((r1 - mu) * (r1 - mu) * i2v) : 0.f;
    gtab[i * P_ + p1] = g1;
  }
}

// ---------------- main: masked-weighted exp-sum of out@out.T ----------------
__device__ __forceinline__ void gload16(void* ldsdst, const void* gsrc) {
  __builtin_amdgcn_global_load_lds(
      (const __attribute__((address_space(1))) unsigned int*)gsrc,
      (__attribute__((address_space(3))) unsigned int*)ldsdst, 16, 0, 0);
}

__global__ __launch_bounds__(512, 2) void tot_kernel(
    const __hip_bfloat16* __restrict__ outb, const float* __restrict__ gtab,
    const int* __restrict__ hq, float* __restrict__ sums) {
  __shared__ __align__(16) char lds[65536];  // A:[0,32K) B:[32K,64K), rows of 256B
  const int tid = threadIdx.x, lane = tid & 63, wid = tid >> 6;
  const int i0 = blockIdx.y * 128, j0 = blockIdx.x * 128;
  const int wr = wid >> 2, wc = wid & 3;

  f32x4 acc[4][2] = {};

  const int wseg = wid & 3;
  const bool isB = (wid >= 4);
  const int growbase = isB ? j0 : i0;
  char* panel = lds + (isB ? 32768 : 0);

  for (int kk = 0; kk < 2; ++kk) {
    // stage 32 rows/wave of the 128x128-element (bf16) half-K panel, swizzled source
#pragma unroll
    for (int it = 0; it < 8; ++it) {
      int rbase = wseg * 32 + it * 4;
      int row = rbase + (lane >> 4);
      int c = lane & 15;
      int src = (growbase + row) * D_ + kk * 128 + ((c ^ (row & 7)) * 8);
      gload16(panel + rbase * 256, outb + src);
    }
    __syncthreads();  // drains vmcnt before barrier
#pragma unroll
    for (int ks = 0; ks < 4; ++ks) {
      bf16x8 af[4], bf[2];
#pragma unroll
      for (int m = 0; m < 4; ++m) {
        int row = wr * 64 + m * 16 + (lane & 15);
        int off = row * 256 + ((((ks << 2) + (lane >> 4)) ^ (row & 7)) << 4);
        af[m] = *(const bf16x8*)(lds + off);
      }
#pragma unroll
      for (int n = 0; n < 2; ++n) {
        int row = wc * 32 + n * 16 + (lane & 15);
        int off = 32768 + row * 256 + ((((ks << 2) + (lane >> 4)) ^ (row & 7)) << 4);
        bf[n] = *(const bf16x8*)(lds + off);
      }
#pragma unroll
      for (int m = 0; m < 4; ++m)
#pragma unroll
        for (int n = 0; n < 2; ++n)
          acc[m][n] = __builtin_amdgcn_mfma_f32_16x16x32_bf16(af[m], bf[n], acc[m][n], 0, 0, 0);
    }
    __syncthreads();  // all reads done before restage
  }

  // epilogue: s -> Gtab[i][hq[j]] * exp(s/T), excluding diagonal
  int jc = j0 + wc * 32 + (lane & 15);
  int hqa = hq[jc], hqb = hq[jc + 16];
  float local = 0.f;
#pragma unroll
  for (int m = 0; m < 4; ++m) {
    int ib = i0 + wr * 64 + m * 16 + ((lane >> 4) << 2);
#pragma unroll
    for (int r = 0; r < 4; ++r) {
      int i = ib + r;
      const float* grow = gtab + i * P_;
      float sa = acc[m][0][r];
      if (i != jc) local += grow[hqa] * __expf(sa * INVT);
      float sb = acc[m][1][r];
      if (i != jc + 16) local += grow[hqb] * __expf(sb * INVT);
    }
  }
  local = waveReduceSum(local);
  __shared__ float s8[8];
  if (lane == 0) s8[wid] = local;
  __syncthreads();
  if (tid == 0) {
    float t = 0.f;
#pragma unroll
    for (int w = 0; w < 8; ++w) t += s8[w];
    atomicAdd(&sums[0], t);
  }
}

// ---------------- finish: loss ----------------
__global__ void finish_kernel(const float* __restrict__ sums, float* __restrict__ out) {
  out[0] = logf(sums[0]) - sums[1] * (INVT / (float)B_);
}

extern "C" void kernel_launch(void* const* d_in, const int* in_sizes, int n_in,
                              void* d_out, int out_size, void* d_ws, size_t ws_size,
                              hipStream_t stream) {
  const float* x   = (const float*)d_in[0];
  const float* xa  = (const float*)d_in[1];
  const float* pw  = (const float*)d_in[2];
  const int* hq1   = (const int*)d_in[3];
  const int* hq2   = (const int*)d_in[4];
  const int* nq1   = (const int*)d_in[5];
  const int* nq2   = (const int*)d_in[6];
  float* out = (float*)d_out;

  char* ws = (char*)d_ws;
  __hip_bfloat16* outb = (__hip_bfloat16*)(ws);                 // 2,097,152 B
  float* gtab = (float*)(ws + 2097152);                          // 1,638,400 B
  float* w    = (float*)(ws + 2097152 + 1638400);                // 102,400 B
  float* pd   = (float*)(ws + 2097152 + 1638400 + 102400);       // 40,000 B
  int*   hq   = (int*)  (ws + 2097152 + 1638400 + 102400 + 40064); // 16,384 B
  int*   cnt  = (int*)  (ws + 2097152 + 1638400 + 102400 + 40064 + 16384); // 400 B
  float* sums = (float*)(ws + 2097152 + 1638400 + 102400 + 40064 + 16384 + 512); // 8 B

  init_kernel<<<1, 64, 0, stream>>>(sums);
  norm_kernel<<<B_, 256, 0, stream>>>(x, xa, outb, sums);
  pnorm_kernel<<<P_, 256, 0, stream>>>(pw, w);
  pd_kernel<<<P_, 256, 0, stream>>>(w, pd);
  hist_kernel<<<1, 256, 0, stream>>>(hq1, hq2, hq, cnt);
  gtab_kernel<<<N_ / 4, 256, 0, stream>>>(hq, cnt, pd, nq1, nq2, gtab);
  tot_kernel<<<dim3(32, 32), 512, 0, stream>>>(outb, gtab, hq, sums);
  finish_kernel<<<1, 1, 0, stream>>>(sums, out);
}

// Round 2
// 126.125 us; speedup vs baseline: 1.2280x; 1.2280x over previous
//
#include <hip/hip_runtime.h>
#include <hip/hip_bf16.h>
#include <cstdint>

#define B_ 2048
#define N_ 4096
#define D_ 256
#define P_ 100
#define K_ 30
#define INVT 5.0f

typedef __attribute__((ext_vector_type(8))) short bf16x8;
typedef __attribute__((ext_vector_type(4))) float f32x4;
typedef __attribute__((ext_vector_type(4))) unsigned short us4;

__device__ __forceinline__ float waveReduceSum(float v) {
#pragma unroll
  for (int off = 32; off > 0; off >>= 1) v += __shfl_xor(v, off, 64);
  return v;
}

__device__ __forceinline__ float blockReduceSum256(float v, float* s4) {
  int lane = threadIdx.x & 63, w = threadIdx.x >> 6;
  v = waveReduceSum(v);
  __syncthreads();
  if (lane == 0) s4[w] = v;
  __syncthreads();
  return s4[0] + s4[1] + s4[2] + s4[3];
}

__device__ __forceinline__ unsigned short f2bf(float f) {
  __hip_bfloat16 h = __float2bfloat16(f);
  return *reinterpret_cast<unsigned short*>(&h);
}
__device__ __forceinline__ float bf2f(unsigned short u) {
  return __uint_as_float(((unsigned int)u) << 16);
}

// ---- K1: block 0 = zero sums + hist/concat; blocks 1..100 = proto inv-norms ----
__global__ void prep_kernel(const float* __restrict__ pw, const int* __restrict__ hq1,
                            const int* __restrict__ hq2, int* __restrict__ hq,
                            int* __restrict__ cnt, float* __restrict__ pninv,
                            float* __restrict__ sums) {
  __shared__ int c[P_];
  __shared__ float s4[4];
  int t = threadIdx.x;
  if (blockIdx.x == 0) {
    if (t < 2) sums[t] = 0.f;
    if (t < P_) c[t] = 0;
    __syncthreads();
    for (int i = t; i < N_; i += 256) {
      int q = (i < B_) ? hq1[i] : hq2[i - B_];
      hq[i] = q;
      atomicAdd(&c[q], 1);
    }
    __syncthreads();
    if (t < P_) cnt[t] = c[t];
  } else {
    int r = blockIdx.x - 1;
    float a = pw[r * D_ + t];
    float ss = blockReduceSum256(a * a, s4);
    if (t == 0) pninv[r] = 1.f / fmaxf(sqrtf(ss), 1e-12f);
  }
}

// ---- K2: blocks 0..511 = row normalize (1 wave/row) + pos dots; 512..611 = proto_dist ----
__global__ void normpd_kernel(const float* __restrict__ x, const float* __restrict__ xa,
                              const float* __restrict__ pw, const float* __restrict__ pninv,
                              __hip_bfloat16* __restrict__ outb, float* __restrict__ pd,
                              float* __restrict__ sums) {
  __shared__ float s4[4];
  __shared__ float wq[D_];
  int t = threadIdx.x, lane = t & 63, wv = t >> 6;
  if (blockIdx.x < 512) {
    int i = blockIdx.x * 4 + wv;
    float4 a = ((const float4*)(x + i * D_))[lane];
    float ss = waveReduceSum(a.x * a.x + a.y * a.y + a.z * a.z + a.w * a.w);
    float inv1 = 1.f / fmaxf(sqrtf(ss), 1e-12f);
    float o1x = a.x * inv1, o1y = a.y * inv1, o1z = a.z * inv1, o1w = a.w * inv1;
    us4 p1; p1[0] = f2bf(o1x); p1[1] = f2bf(o1y); p1[2] = f2bf(o1z); p1[3] = f2bf(o1w);
    ((us4*)(outb + i * D_))[lane] = p1;
    float4 b = ((const float4*)(xa + i * D_))[lane];
    float ss2 = waveReduceSum(b.x * b.x + b.y * b.y + b.z * b.z + b.w * b.w);
    float inv2 = 1.f / fmaxf(sqrtf(ss2), 1e-12f);
    float o2x = b.x * inv2, o2y = b.y * inv2, o2z = b.z * inv2, o2w = b.w * inv2;
    us4 p2; p2[0] = f2bf(o2x); p2[1] = f2bf(o2y); p2[2] = f2bf(o2z); p2[3] = f2bf(o2w);
    ((us4*)(outb + (B_ + i) * D_))[lane] = p2;
    float d = waveReduceSum(o1x * o2x + o1y * o2y + o1z * o2z + o1w * o2w);
    if (lane == 0) s4[wv] = d;
    __syncthreads();
    if (t == 0) atomicAdd(&sums[1], s4[0] + s4[1] + s4[2] + s4[3]);
  } else {
    int q = blockIdx.x - 512;
    wq[t] = pw[q * D_ + t];
    __syncthreads();
    float nq = pninv[q];
    for (int r = wv; r < P_; r += 4) {
      float4 b = ((const float4*)(pw + r * D_))[lane];
      float s = wq[lane * 4] * b.x + wq[lane * 4 + 1] * b.y +
                wq[lane * 4 + 2] * b.z + wq[lane * 4 + 3] * b.w;
      s = waveReduceSum(s);
      if (lane == 0) pd[q * P_ + r] = s * nq * pninv[r];
    }
  }
}

// ---- K3: per-row Gtab[i][p] (bf16) = member ? reweight : 0 ----
__global__ void gtab_kernel(const int* __restrict__ hq, const int* __restrict__ cnt,
                            const float* __restrict__ pd, const int* __restrict__ nq1,
                            const int* __restrict__ nq2, unsigned short* __restrict__ gtabh) {
  __shared__ unsigned char memb[4][104];
  int wv = threadIdx.x >> 6, lane = threadIdx.x & 63;
  int i = blockIdx.x * 4 + wv;
  int q = hq[i];
  if (lane < 52) { memb[wv][lane * 2] = 0; memb[wv][lane * 2 + 1] = 0; }
  __syncthreads();
  const int* nrow = (i < B_) ? (nq1 + i * K_) : (nq2 + (i - B_) * K_);
  if (lane < K_) memb[wv][nrow[lane]] = 1;
  __syncthreads();

  int p0 = lane, p1 = lane + 64;
  bool has1 = (p1 < P_);
  float v0 = pd[q * P_ + p0];
  int m0 = cnt[p0] - (p0 == q ? 1 : 0);
  float v1 = 0.f; int m1 = 0;
  if (has1) { v1 = pd[q * P_ + p1]; m1 = cnt[p1] - (p1 == q ? 1 : 0); }

  float mn = 1e30f, mx = -1e30f;
  if (m0 > 0) { mn = fminf(mn, v0); mx = fmaxf(mx, v0); }
  if (has1 && m1 > 0) { mn = fminf(mn, v1); mx = fmaxf(mx, v1); }
#pragma unroll
  for (int off = 32; off > 0; off >>= 1) {
    mn = fminf(mn, __shfl_xor(mn, off, 64));
    mx = fmaxf(mx, __shfl_xor(mx, off, 64));
  }
  float rmin = fminf(0.f, mn);
  float rmax = fmaxf(rmin, mx);
  float inv = 1.f / (rmax - rmin);
  float r0 = (v0 - rmin) * inv, r1 = (v1 - rmin) * inv;
  float s1 = (m0 > 0 ? (float)m0 * r0 : 0.f) + ((has1 && m1 > 0) ? (float)m1 * r1 : 0.f);
  s1 = waveReduceSum(s1);
  float mu = s1 / (float)N_;
  float ss = (m0 > 0 ? (float)m0 * (r0 - mu) * (r0 - mu) : 0.f) +
             ((has1 && m1 > 0) ? (float)m1 * (r1 - mu) * (r1 - mu) : 0.f);
  ss = waveReduceSum(ss);
  ss += mu * mu;
  float var = ss / (float)(N_ - 1);
  float i2v = 1.f / (2.f * var);
  float g0 = memb[wv][p0] ? __expf((r0 - mu) * (r0 - mu) * i2v) : 0.f;
  gtabh[i * P_ + p0] = f2bf(g0);
  if (has1) {
    float g1 = memb[wv][p1] ? __expf((r1 - mu) * (r1 - mu) * i2v) : 0.f;
    gtabh[i * P_ + p1] = f2bf(g1);
  }
}

// ---- K4: triangle-tiled masked-weighted exp-sum of out@out.T ----
__device__ __forceinline__ void gload16(void* ldsdst, const void* gsrc) {
  __builtin_amdgcn_global_load_lds(
      (const __attribute__((address_space(1))) unsigned int*)gsrc,
      (__attribute__((address_space(3))) unsigned int*)ldsdst, 16, 0, 0);
}

__global__ __launch_bounds__(512, 2) void tot_kernel(
    const __hip_bfloat16* __restrict__ outb, const unsigned short* __restrict__ gtabh,
    const int* __restrict__ hq, float* __restrict__ sums) {
  __shared__ __align__(16) char lds[65536];  // A:[0,32K) B:[32K,64K), 256B rows
  __shared__ float s8[8];
  const int tid = threadIdx.x, lane = tid & 63, wid = tid >> 6;

  // triangle decode: k -> (bi, bj), bi <= bj, 32x32 tile grid
  int rem = blockIdx.x, bi = 0;
  while (rem >= 32 - bi) { rem -= 32 - bi; ++bi; }
  const int bj = bi + rem;
  const bool offdiag = (bi != bj);
  const int i0 = bi * 128, j0 = bj * 128;
  const int wr = wid >> 2, wc = wid & 3;

  f32x4 acc[4][2] = {};

  const int wseg = wid & 3;
  const bool isB = (wid >= 4);
  const int growbase = isB ? j0 : i0;
  char* panel = lds + (isB ? 32768 : 0);

  for (int kk = 0; kk < 2; ++kk) {
#pragma unroll
    for (int it = 0; it < 8; ++it) {
      int rbase = wseg * 32 + it * 4;
      int row = rbase + (lane >> 4);
      int c = lane & 15;
      int src = (growbase + row) * D_ + kk * 128 + ((c ^ (row & 7)) * 8);
      gload16(panel + rbase * 256, outb + src);
    }
    __syncthreads();
#pragma unroll
    for (int ks = 0; ks < 4; ++ks) {
      bf16x8 af[4], bfr[2];
#pragma unroll
      for (int m = 0; m < 4; ++m) {
        int row = wr * 64 + m * 16 + (lane & 15);
        int off = row * 256 + ((((ks << 2) + (lane >> 4)) ^ (row & 7)) << 4);
        af[m] = *(const bf16x8*)(lds + off);
      }
#pragma unroll
      for (int n = 0; n < 2; ++n) {
        int row = wc * 32 + n * 16 + (lane & 15);
        int off = 32768 + row * 256 + ((((ks << 2) + (lane >> 4)) ^ (row & 7)) << 4);
        bfr[n] = *(const bf16x8*)(lds + off);
      }
#pragma unroll
      for (int m = 0; m < 4; ++m)
#pragma unroll
        for (int n = 0; n < 2; ++n)
          acc[m][n] = __builtin_amdgcn_mfma_f32_16x16x32_bf16(af[m], bfr[n], acc[m][n], 0, 0, 0);
    }
    __syncthreads();  // all LDS reads done before restage / epilogue reuse
  }

  // ---- epilogue: stage gtab rows (bf16) + hq into LDS, then gather locally ----
  unsigned short* ga = (unsigned short*)lds;            // [128][104]
  unsigned short* gb = (unsigned short*)(lds + 26624);  // [128][104]
  int* hqA = (int*)(lds + 53248);
  int* hqB = (int*)(lds + 53760);
  for (int idx = tid; idx < 128 * P_; idx += 512) {
    int r = idx / P_, c = idx - r * P_;
    ga[r * 104 + c] = gtabh[(i0 + r) * P_ + c];
    gb[r * 104 + c] = gtabh[(j0 + r) * P_ + c];
  }
  if (tid < 128) hqA[tid] = hq[i0 + tid];
  else if (tid < 256) hqB[tid - 128] = hq[j0 + tid - 128];
  __syncthreads();

  const int jl0 = wc * 32 + (lane & 15);
  const int jl1 = jl0 + 16;
  const int hj0 = hqB[jl0], hj1 = hqB[jl1];
  float local = 0.f;
#pragma unroll
  for (int m = 0; m < 4; ++m) {
    int ilb = wr * 64 + m * 16 + ((lane >> 4) << 2);
#pragma unroll
    for (int r = 0; r < 4; ++r) {
      int il = ilb + r;
      float e0 = __expf(acc[m][0][r] * INVT);
      float e1 = __expf(acc[m][1][r] * INVT);
      float wa0 = bf2f(ga[il * 104 + hj0]);
      float wa1 = bf2f(ga[il * 104 + hj1]);
      if (offdiag) {
        int hi = hqA[il];
        float wb0 = bf2f(gb[jl0 * 104 + hi]);
        float wb1 = bf2f(gb[jl1 * 104 + hi]);
        local += (wa0 + wb0) * e0 + (wa1 + wb1) * e1;
      } else {
        if (il != jl0) local += wa0 * e0;
        if (il != jl1) local += wa1 * e1;
      }
    }
  }
  local = waveReduceSum(local);
  if (lane == 0) s8[wid] = local;
  __syncthreads();
  if (tid == 0) {
    float t = 0.f;
#pragma unroll
    for (int w = 0; w < 8; ++w) t += s8[w];
    atomicAdd(&sums[0], t);
  }
}

// ---- K5: finish ----
__global__ void finish_kernel(const float* __restrict__ sums, float* __restrict__ out) {
  out[0] = logf(sums[0]) - sums[1] * (INVT / (float)B_);
}

extern "C" void kernel_launch(void* const* d_in, const int* in_sizes, int n_in,
                              void* d_out, int out_size, void* d_ws, size_t ws_size,
                              hipStream_t stream) {
  const float* x   = (const float*)d_in[0];
  const float* xa  = (const float*)d_in[1];
  const float* pw  = (const float*)d_in[2];
  const int* hq1   = (const int*)d_in[3];
  const int* hq2   = (const int*)d_in[4];
  const int* nq1   = (const int*)d_in[5];
  const int* nq2   = (const int*)d_in[6];
  float* out = (float*)d_out;

  char* ws = (char*)d_ws;
  __hip_bfloat16* outb  = (__hip_bfloat16*)(ws);               // 2,097,152 B
  unsigned short* gtabh = (unsigned short*)(ws + 2097152);     // 819,200 B
  float* pd    = (float*)(ws + 2916352);                       // 40,000 B
  float* pninv = (float*)(ws + 2956352);                       // 400 B
  int*   hq    = (int*)  (ws + 2956800);                       // 16,384 B
  int*   cnt   = (int*)  (ws + 2973184);                       // 400 B
  float* sums  = (float*)(ws + 2973696);                       // 8 B

  prep_kernel<<<101, 256, 0, stream>>>(pw, hq1, hq2, hq, cnt, pninv, sums);
  normpd_kernel<<<612, 256, 0, stream>>>(x, xa, pw, pninv, outb, pd, sums);
  gtab_kernel<<<N_ / 4, 256, 0, stream>>>(hq, cnt, pd, nq1, nq2, gtabh);
  tot_kernel<<<528, 512, 0, stream>>>(outb, gtabh, hq, sums);
  finish_kernel<<<1, 1, 0, stream>>>(sums, out);
}